// Round 3
// baseline (386.780 us; speedup 1.0000x reference)
//
#include <hip/hip_runtime.h>
#include <hip/hip_bf16.h>

#define NB 128      // batch
#define NT 128      // Tm1
#define ND 128      // input size (drivers)
#define NH 64       // hidden
#define NTH 1024    // threads per block
#define ESTR 144    // Ebt row stride (ushorts)

__device__ __forceinline__ float fexp2(float x) { return __builtin_amdgcn_exp2f(x); }
__device__ __forceinline__ float frcp (float x) { return __builtin_amdgcn_rcpf(x); }

// DPP-based partial-sum add: v += lane-permuted(v)
template<int CTRL>
__device__ __forceinline__ float dppadd(float v) {
  return v + __int_as_float(__builtin_amdgcn_update_dpp(
      0, __float_as_int(v), CTRL, 0xF, 0xF, true));
}
// sum over each 16-lane group (xor1, xor2, mirror8, mirror16)
__device__ __forceinline__ float sum16(float v) {
  v = dppadd<0xB1>(v);   // quad_perm [1,0,3,2]
  v = dppadd<0x4E>(v);   // quad_perm [2,3,0,1]
  v = dppadd<0x141>(v);  // row_half_mirror
  v = dppadd<0x140>(v);  // row_mirror
  return v;
}

// f32 -> bf16 bits, round-to-nearest-even
__device__ __forceinline__ unsigned short f2bf(float f) {
  unsigned u = __float_as_uint(f);
  u += 0x7fffu + ((u >> 16) & 1u);
  return (unsigned short)(u >> 16);
}

__global__ __launch_bounds__(NTH) void darnn_enc(
    const float* __restrict__ x,     // [B][T1][D]
    const float* __restrict__ Wehs,  // [T1][2H]
    const float* __restrict__ behs,  // [T1]
    const float* __restrict__ Ue,    // [T1][T1]
    const float* __restrict__ Ueb,   // [T1]
    const float* __restrict__ vew,   // [T1]
    const float* __restrict__ Wih,   // [4H][D]
    const float* __restrict__ Whh,   // [4H][H]
    const float* __restrict__ bih,   // [256]
    const float* __restrict__ bhh,   // [256]
    float* __restrict__ out)
{
  constexpr float C2  = 2.88539008177792681f;  // 2*log2(e)
  constexpr float L2E = 1.44269504088896340f;  // log2(e)

  __shared__ __align__(16) float          xh[NT][ND];     // 64K: x, overwritten by x_hat
  __shared__ __align__(16) unsigned short Ebt[ND][ESTR];  // 36.9K: E bf16 (prologue)
  __shared__ __align__(16) float          hbuf[NT][NH];   // 32K: h outputs (prologue: UeTc)
  __shared__ __align__(16) float          hq[2][16][6];   // h chunks of 4, padded, dbuf
  __shared__ __align__(16) float          cq[2][16][6];   // c chunks of 4, padded, dbuf
  __shared__ __align__(16) float          wvp[16][12];    // w_s = exp(2*we) chunked+padded
  __shared__ __align__(16) float          xpad[16][10];   // ex = e*x chunks of 8, padded
  __shared__ __align__(16) float          part[16];       // per-wave sum of e

  const int b    = blockIdx.x;
  const int tid  = threadIdx.x;
  const int lane = tid & 63;
  const int wid  = tid >> 6;
  const float* xb = x + b * (NT * ND);

  // ---------------- stage x into LDS ---------------------------------------
#pragma unroll
  for (int i = 0; i < 4; ++i) {
    const int f = i * 1024 + tid;
    const int t = f >> 5, c = (f & 31) << 2;
    *reinterpret_cast<float4*>(&xh[t][c]) =
        *reinterpret_cast<const float4*>(xb + t * ND + c);
  }
  float (*UeTc)[33] = reinterpret_cast<float(*)[33]>(&hbuf[0][0]);
  __syncthreads();

  // ---------------- Prologue: E[d][s] = exp(2*(x_perm @ Ue^T + Ueb)) --------
  {
    const int dq = tid & 31;
    const int sg = tid >> 5;
    float acc[16];
#pragma unroll
    for (int i = 0; i < 16; ++i) acc[i] = 0.f;
    for (int c = 0; c < 4; ++c) {
      {
        const int ss = 32 * c + sg;
        const int t4 = dq * 4;
        const float4 u4 = *reinterpret_cast<const float4*>(Ue + ss * NT + t4);
        UeTc[t4 + 0][sg] = u4.x;
        UeTc[t4 + 1][sg] = u4.y;
        UeTc[t4 + 2][sg] = u4.z;
        UeTc[t4 + 3][sg] = u4.w;
      }
      __syncthreads();
#pragma unroll 4
      for (int t = 0; t < NT; ++t) {
        const float4 xv = *reinterpret_cast<const float4*>(&xh[t][4 * dq]);
        const float u = UeTc[t][sg];
        acc[4*c+0] = fmaf(xv.x, u, acc[4*c+0]);
        acc[4*c+1] = fmaf(xv.y, u, acc[4*c+1]);
        acc[4*c+2] = fmaf(xv.z, u, acc[4*c+2]);
        acc[4*c+3] = fmaf(xv.w, u, acc[4*c+3]);
      }
      __syncthreads();
    }
#pragma unroll
    for (int c = 0; c < 4; ++c) {
      const int ss = sg + 32 * c;
      const float ub = Ueb[ss];
#pragma unroll
      for (int di = 0; di < 4; ++di) {
        const float e = fexp2(C2 * (acc[4*c+di] + ub));
        Ebt[4*dq + di][ss] = f2bf(e);
      }
    }
  }
  __syncthreads();   // Ebt complete before register loads

  // zero h/c state (both parities)
  if (tid < 192) (&hq[0][0][0])[tid] = 0.f;
  if (tid < 192) (&cq[0][0][0])[tid] = 0.f;

  // ---------------- persistent per-thread registers -------------------------
  // phase A: 8 threads per s
  const int s_a = tid >> 3, r_a = tid & 7;
  float wehs_r[16];
#pragma unroll
  for (int i = 0; i < 4; ++i) {
    const float4 v4 = *reinterpret_cast<const float4*>(Wehs + s_a * 128 + r_a * 16 + 4 * i);
    wehs_r[4*i+0] = v4.x; wehs_r[4*i+1] = v4.y; wehs_r[4*i+2] = v4.z; wehs_r[4*i+3] = v4.w;
  }
  const float behs_r = behs[s_a];

  // phase B: lane = s_l + 16*dp; d0 = 8*wid + 2*dp
  const int s_l = lane & 15;
  const int dp  = lane >> 4;
  const int d0  = 8 * wid + 2 * dp;
  float m2vw[8];
  {
    const float4 va = *reinterpret_cast<const float4*>(vew + 8 * s_l);
    const float4 vb = *reinterpret_cast<const float4*>(vew + 8 * s_l + 4);
    m2vw[0] = -2.f * va.x; m2vw[1] = -2.f * va.y; m2vw[2] = -2.f * va.z; m2vw[3] = -2.f * va.w;
    m2vw[4] = -2.f * vb.x; m2vw[5] = -2.f * vb.y; m2vw[6] = -2.f * vb.z; m2vw[7] = -2.f * vb.w;
  }
  // E fragments into registers (time-invariant)
  int er[8];
  {
    const int4 ea = *reinterpret_cast<const int4*>(&Ebt[d0][8 * s_l]);
    const int4 eb = *reinterpret_cast<const int4*>(&Ebt[d0 + 1][8 * s_l]);
    er[0] = ea.x; er[1] = ea.y; er[2] = ea.z; er[3] = ea.w;
    er[4] = eb.x; er[5] = eb.y; er[6] = eb.z; er[7] = eb.w;
  }

  // phase D+E: lane = 16*kk + cD; unit kD = 4*wid + kk; all 4 gates per lane
  const int kk = lane >> 4, cD = lane & 15;
  const int kD = 4 * wid + kk;
  float wxr[4][8], whr[4][4], b4[4];
#pragma unroll
  for (int g = 0; g < 4; ++g) {
    const int j = 64 * g + kD;
    const float4 u0 = *reinterpret_cast<const float4*>(Wih + j * 128 + 8 * cD);
    const float4 u1 = *reinterpret_cast<const float4*>(Wih + j * 128 + 8 * cD + 4);
    wxr[g][0] = u0.x; wxr[g][1] = u0.y; wxr[g][2] = u0.z; wxr[g][3] = u0.w;
    wxr[g][4] = u1.x; wxr[g][5] = u1.y; wxr[g][6] = u1.z; wxr[g][7] = u1.w;
    const float4 u2 = *reinterpret_cast<const float4*>(Whh + j * 64 + 4 * cD);
    whr[g][0] = u2.x; whr[g][1] = u2.y; whr[g][2] = u2.z; whr[g][3] = u2.w;
    b4[g] = bih[j] + bhh[j];
  }

  __syncthreads();

  // ---------------- main recurrence: 3 barriers/step, no global mem ---------
  int p = 0;
  for (int t = 0; t < NT; ++t) {
    // ---- A: we[s] = behs[s] + hc . Wehs[s,:];  w_s = exp(2*we)
    {
      const float* src = (r_a < 4) ? &hq[p][4 * (r_a & 3)][0] : &cq[p][4 * (r_a & 3)][0];
      float a0 = 0.f;
#pragma unroll
      for (int i = 0; i < 4; ++i) {
        const float4 h4 = *reinterpret_cast<const float4*>(src + 6 * i);
        a0 = fmaf(h4.x, wehs_r[4*i+0], a0);
        a0 = fmaf(h4.y, wehs_r[4*i+1], a0);
        a0 = fmaf(h4.z, wehs_r[4*i+2], a0);
        a0 = fmaf(h4.w, wehs_r[4*i+3], a0);
      }
      a0 = dppadd<0xB1>(a0);
      a0 = dppadd<0x4E>(a0);
      a0 = dppadd<0x141>(a0);
      if (r_a == 0) wvp[s_a >> 3][s_a & 7] = fexp2(C2 * (a0 + behs_r));
    }
    __syncthreads();

    // ---- B': v[d] -> e[d] = exp(v); writers stage ex = e*x; wave partial Σe
    {
      const float4 wa = *reinterpret_cast<const float4*>(&wvp[s_l][0]);
      const float4 wb = *reinterpret_cast<const float4*>(&wvp[s_l][4]);
      const float wj0 = wa.x, wj1 = wa.y, wj2 = wa.z, wj3 = wa.w;
      const float wj4 = wb.x, wj5 = wb.y, wj6 = wb.z, wj7 = wb.w;
      float a0 = 0.f, a1 = 0.f;
      unsigned u;
      u = (unsigned)er[0];
      a0 = fmaf(m2vw[0], frcp(fmaf(wj0, __uint_as_float(u << 16),         1.f)), a0);
      a0 = fmaf(m2vw[1], frcp(fmaf(wj1, __uint_as_float(u & 0xffff0000u), 1.f)), a0);
      u = (unsigned)er[1];
      a0 = fmaf(m2vw[2], frcp(fmaf(wj2, __uint_as_float(u << 16),         1.f)), a0);
      a0 = fmaf(m2vw[3], frcp(fmaf(wj3, __uint_as_float(u & 0xffff0000u), 1.f)), a0);
      u = (unsigned)er[2];
      a0 = fmaf(m2vw[4], frcp(fmaf(wj4, __uint_as_float(u << 16),         1.f)), a0);
      a0 = fmaf(m2vw[5], frcp(fmaf(wj5, __uint_as_float(u & 0xffff0000u), 1.f)), a0);
      u = (unsigned)er[3];
      a0 = fmaf(m2vw[6], frcp(fmaf(wj6, __uint_as_float(u << 16),         1.f)), a0);
      a0 = fmaf(m2vw[7], frcp(fmaf(wj7, __uint_as_float(u & 0xffff0000u), 1.f)), a0);
      u = (unsigned)er[4];
      a1 = fmaf(m2vw[0], frcp(fmaf(wj0, __uint_as_float(u << 16),         1.f)), a1);
      a1 = fmaf(m2vw[1], frcp(fmaf(wj1, __uint_as_float(u & 0xffff0000u), 1.f)), a1);
      u = (unsigned)er[5];
      a1 = fmaf(m2vw[2], frcp(fmaf(wj2, __uint_as_float(u << 16),         1.f)), a1);
      a1 = fmaf(m2vw[3], frcp(fmaf(wj3, __uint_as_float(u & 0xffff0000u), 1.f)), a1);
      u = (unsigned)er[6];
      a1 = fmaf(m2vw[4], frcp(fmaf(wj4, __uint_as_float(u << 16),         1.f)), a1);
      a1 = fmaf(m2vw[5], frcp(fmaf(wj5, __uint_as_float(u & 0xffff0000u), 1.f)), a1);
      u = (unsigned)er[7];
      a1 = fmaf(m2vw[6], frcp(fmaf(wj6, __uint_as_float(u << 16),         1.f)), a1);
      a1 = fmaf(m2vw[7], frcp(fmaf(wj7, __uint_as_float(u & 0xffff0000u), 1.f)), a1);
      a0 = sum16(a0);
      a1 = sum16(a1);
      const float e0 = fexp2(L2E * a0);
      const float e1 = fexp2(L2E * a1);
      float ps = e0 + e1;
      ps += __int_as_float(__builtin_amdgcn_ds_swizzle(__float_as_int(ps), 0x401F)); // xor16
      ps += __shfl_xor(ps, 32);
      if (lane == 0) part[wid] = ps;
      if (s_l == 0) {
        xpad[wid][2 * dp]     = e0 * xh[t][d0];
        xpad[wid][2 * dp + 1] = e1 * xh[t][d0 + 1];
      }
    }
    __syncthreads();

    // ---- D+E: gates + LSTM cell (4 gates per lane, DPP reduce, no shuffles)
    {
      float tot = part[lane & 15];
      tot = sum16(tot);
      const float rs = frcp(tot);
      const float4 x0 = *reinterpret_cast<const float4*>(&xpad[cD][0]);
      const float4 x1 = *reinterpret_cast<const float4*>(&xpad[cD][4]);
      const float4 h4 = *reinterpret_cast<const float4*>(&hq[p][cD][0]);
      const float xs0 = x0.x * rs, xs1 = x0.y * rs, xs2 = x0.z * rs, xs3 = x0.w * rs;
      const float xs4 = x1.x * rs, xs5 = x1.y * rs, xs6 = x1.z * rs, xs7 = x1.w * rs;
      float ac[4];
#pragma unroll
      for (int g = 0; g < 4; ++g) {
        float a = 0.f;
        a = fmaf(xs0, wxr[g][0], a);
        a = fmaf(xs1, wxr[g][1], a);
        a = fmaf(xs2, wxr[g][2], a);
        a = fmaf(xs3, wxr[g][3], a);
        a = fmaf(xs4, wxr[g][4], a);
        a = fmaf(xs5, wxr[g][5], a);
        a = fmaf(xs6, wxr[g][6], a);
        a = fmaf(xs7, wxr[g][7], a);
        a = fmaf(h4.x, whr[g][0], a);
        a = fmaf(h4.y, whr[g][1], a);
        a = fmaf(h4.z, whr[g][2], a);
        a = fmaf(h4.w, whr[g][3], a);
        ac[g] = sum16(a);
      }
      const float gi = ac[0] + b4[0];
      const float gf = ac[1] + b4[1];
      const float gG = ac[2] + b4[2];
      const float go = ac[3] + b4[3];
      const float c_old = cq[p][wid][kk];   // kD>>2 == wid, kD&3 == kk
      const float si = frcp(1.f + fexp2(-L2E * gi));
      const float sf = frcp(1.f + fexp2(-L2E * gf));
      const float tg = 1.f - 2.f * frcp(1.f + fexp2(C2 * gG));
      const float cn = fmaf(sf, c_old, si * tg);
      const float so = frcp(1.f + fexp2(-L2E * go));
      const float tc = 1.f - 2.f * frcp(1.f + fexp2(C2 * cn));
      const float hn = so * tc;
      if (cD == 0) {
        hq[p ^ 1][wid][kk] = hn;
        cq[p ^ 1][wid][kk] = cn;
        hbuf[t][kD] = hn;
      }
      if (wid == 0) {   // x_hat output row (in-place over consumed x row)
        const float exa = xpad[lane >> 3][lane & 7];
        const float exb = xpad[8 + (lane >> 3)][lane & 7];
        xh[t][lane]      = exa * rs;
        xh[t][lane + 64] = exb * rs;
      }
    }
    __syncthreads();
    p ^= 1;
  }

  // ---------------- bulk flush of outputs -----------------------------------
#pragma unroll
  for (int i = 0; i < 4; ++i) {
    const int f = i * 1024 + tid;
    const int t = f >> 5, c = (f & 31) << 2;
    *reinterpret_cast<float4*>(out + b * (NT * ND) + t * ND + c) =
        *reinterpret_cast<const float4*>(&xh[t][c]);
  }
  float* out2 = out + NB * (NT * ND) + b * (NT * NH);
#pragma unroll
  for (int i = 0; i < 2; ++i) {
    const int f = i * 1024 + tid;
    const int t = f >> 4, c = (f & 15) << 2;
    *reinterpret_cast<float4*>(out2 + t * NH + c) =
        *reinterpret_cast<const float4*>(&hbuf[t][c]);
  }
}

extern "C" void kernel_launch(void* const* d_in, const int* in_sizes, int n_in,
                              void* d_out, int out_size, void* d_ws, size_t ws_size,
                              hipStream_t stream) {
  const float* x    = (const float*)d_in[0];
  const float* Wehs = (const float*)d_in[1];
  const float* behs = (const float*)d_in[2];
  const float* Ue   = (const float*)d_in[3];
  const float* Ueb  = (const float*)d_in[4];
  const float* vew  = (const float*)d_in[5];
  // d_in[6] = v_e_b: constant shift before softmax -> no effect, unused.
  const float* Wih  = (const float*)d_in[7];
  const float* Whh  = (const float*)d_in[8];
  const float* bih  = (const float*)d_in[9];
  const float* bhh  = (const float*)d_in[10];
  float* out = (float*)d_out;

  darnn_enc<<<NB, NTH, 0, stream>>>(x, Wehs, behs, Ue, Ueb, vew, Wih, Whh, bih, bhh, out);
}